// Round 1
// baseline (840.551 us; speedup 1.0000x reference)
//
#include <hip/hip_runtime.h>

// WaveLetPooling: input (8, 512, 512, 64) fp32, NHWC-contiguous.
// Outputs ll, lh, hl, hh each (8, 256, 256, 64) fp32, concatenated in d_out.
//
// Mapping: one thread per float4 channel-chunk of one output pixel.
//   idx = ((b*256 + i)*256 + j)*16 + c4        (float4 units)
// Input float4 index of a = inputs[b, 2i, 2j]: (((b*512+2i)*512+2j)*16 + c4.
// Output ll float4 index == idx exactly -> fully coalesced stores.

#define N4_PER_OUT (8 * 256 * 256 * 16)  // float4 elements per output tensor

__global__ __launch_bounds__(256) void wavelet_pool_kernel(
    const float4* __restrict__ in, float4* __restrict__ out) {
    const int idx = blockIdx.x * 256 + threadIdx.x;  // < 8,388,608 < 2^31

    const int c4 = idx & 15;
    const int j  = (idx >> 4) & 255;
    const int i  = (idx >> 12) & 255;
    const int b  = idx >> 20;

    // input float4 index of pixel (b, 2i, 2j), channel chunk c4
    const int ibase = (((b << 9) + (i << 1)) << 9 | (j << 1)) * 16 + c4;
    // = ((b*512 + 2i)*512 + 2j)*16 + c4   (all power-of-2, exact)

    const float4 va = in[ibase];                 // (2i,   2j  )
    const float4 vb = in[ibase + 16];            // (2i,   2j+1)
    const float4 vc = in[ibase + 512 * 16];      // (2i+1, 2j  )
    const float4 vd = in[ibase + 512 * 16 + 16]; // (2i+1, 2j+1)

    float4 ll, lh, hl, hh;
    // per-component Haar combine
    {
        const float sab = va.x + vb.x, scd = vc.x + vd.x;
        const float sac = va.x + vc.x, sbd = vb.x + vd.x;
        const float sad = va.x + vd.x, sbc = vb.x + vc.x;
        ll.x = 0.5f * (sab + scd);
        lh.x = 0.5f * (sbd - sac);
        hl.x = 0.5f * (scd - sab);
        hh.x = 0.5f * (sad - sbc);
    }
    {
        const float sab = va.y + vb.y, scd = vc.y + vd.y;
        const float sac = va.y + vc.y, sbd = vb.y + vd.y;
        const float sad = va.y + vd.y, sbc = vb.y + vc.y;
        ll.y = 0.5f * (sab + scd);
        lh.y = 0.5f * (sbd - sac);
        hl.y = 0.5f * (scd - sab);
        hh.y = 0.5f * (sad - sbc);
    }
    {
        const float sab = va.z + vb.z, scd = vc.z + vd.z;
        const float sac = va.z + vc.z, sbd = vb.z + vd.z;
        const float sad = va.z + vd.z, sbc = vb.z + vc.z;
        ll.z = 0.5f * (sab + scd);
        lh.z = 0.5f * (sbd - sac);
        hl.z = 0.5f * (scd - sab);
        hh.z = 0.5f * (sad - sbc);
    }
    {
        const float sab = va.w + vb.w, scd = vc.w + vd.w;
        const float sac = va.w + vc.w, sbd = vb.w + vd.w;
        const float sad = va.w + vd.w, sbc = vb.w + vc.w;
        ll.w = 0.5f * (sab + scd);
        lh.w = 0.5f * (sbd - sac);
        hl.w = 0.5f * (scd - sab);
        hh.w = 0.5f * (sad - sbc);
    }

    out[idx]                  = ll;
    out[idx + N4_PER_OUT]     = lh;
    out[idx + 2 * N4_PER_OUT] = hl;
    out[idx + 3 * N4_PER_OUT] = hh;
}

extern "C" void kernel_launch(void* const* d_in, const int* in_sizes, int n_in,
                              void* d_out, int out_size, void* d_ws, size_t ws_size,
                              hipStream_t stream) {
    const float4* in = (const float4*)d_in[0];
    float4* out = (float4*)d_out;
    const int n_threads = N4_PER_OUT;       // 8,388,608
    const int block = 256;
    const int grid = n_threads / block;     // 32,768
    wavelet_pool_kernel<<<grid, block, 0, stream>>>(in, out);
}